// Round 1
// 730.522 us; speedup vs baseline: 1.0459x; 1.0459x over previous
//
#include <hip/hip_runtime.h>
#include <math.h>

typedef __attribute__((ext_vector_type(8))) short short8;
typedef __attribute__((ext_vector_type(4))) float f32x4;

namespace {
constexpr int B_ = 8;
constexpr int N_ = 2048;
constexpr int D_ = 1024;
constexpr float NEGV = -1.0e9f;
}

__device__ __forceinline__ unsigned short f2bf(float x) {
    union { float f; unsigned u; } v; v.f = x;
    unsigned u = v.u + 0x7fffu + ((v.u >> 16) & 1u);
    return (unsigned short)(u >> 16);
}

// ---------------------------------------------------------------------------
// Per-batch valid lengths from the prefix mask (uint8 or int32 layout).
// ---------------------------------------------------------------------------
__global__ __launch_bounds__(256)
void k_lengths(const unsigned char* __restrict__ mask, int* __restrict__ L)
{
    const int b = blockIdx.x;
    const int t = threadIdx.x;
    const bool u8 = (mask[1] != 0);
    int cnt = 0;
    if (u8) {
        for (int n = t; n < N_; n += 256)
            cnt += (mask[(size_t)b * N_ + n] != 0) ? 1 : 0;
    } else {
        const int* mi = (const int*)mask;
        for (int n = t; n < N_; n += 256)
            cnt += (mi[(size_t)b * N_ + n] != 0) ? 1 : 0;
    }
    __shared__ int red[256];
    red[t] = cnt;
    __syncthreads();
    for (int s = 128; s > 0; s >>= 1) {
        if (t < s) red[t] += red[t + s];
        __syncthreads();
    }
    if (t == 0) L[b] = red[0];
}

// ---------------------------------------------------------------------------
// f32 -> bf16 conversion (with optional scale), 1 float4 per thread.
// ---------------------------------------------------------------------------
__global__ __launch_bounds__(256)
void convert_bf16(const float* __restrict__ in, unsigned short* __restrict__ out,
                  int n4, float alpha)
{
    const int i = blockIdx.x * 256 + threadIdx.x;
    if (i >= n4) return;
    const float4 v = ((const float4*)in)[i];
    ushort4 o;
    o.x = f2bf(v.x * alpha); o.y = f2bf(v.y * alpha);
    o.z = f2bf(v.z * alpha); o.w = f2bf(v.w * alpha);
    ((ushort4*)out)[i] = o;
}

// ---------------------------------------------------------------------------
// bf16 MFMA NT-GEMM: C[m][n] = sum_k A[m][k] * B[n][k]
// 128x128 block tile, BK=32, 256 threads (4 waves, 2x2 of 64x64),
// 16x16x32 MFMA, global_load_lds width-16 staging.
//
// LDS geometry: row = 32 shorts (64 B). 16-B segment s_log of row m is
// stored at physical segment s_log ^ ((m>>1)&3). Fragment ds_read_b128 for
// lane (q=lane>>4, r=lane&15) then hits bank base 16*(r&1) + 4*(q^((r>>1)&3)):
// each 8-lane batch covers all 8 four-bank groups -> conflict-free.
//
// XCD swizzle: hw linear block id % 8 == XCD (8 XCDs, private 4MB L2 each).
// Remap so each XCD owns a contiguous logical chunk of the grid: blocks
// sharing A-panels (and, for batched launches, the same batch) land on one
// XCD, making panel re-reads L2 hits instead of cross-XCD re-fetches.
// Bijective when total % 8 == 0 (all launches here); identity fallback else.
//
// OUT_MODE: 0 = f32, 1 = bf16, 2 = f32 with prefix mask (logits)
// ---------------------------------------------------------------------------
template <int OUT_MODE>
__global__ __launch_bounds__(256)
void gemm_nt_mfma(const unsigned short* __restrict__ A, int lda, long strideA,
                  const unsigned short* __restrict__ Bm, int ldb, long strideB,
                  void* __restrict__ Cout, int ldc, long strideC,
                  int K, const int* __restrict__ Lp)
{
    __shared__ __attribute__((aligned(16))) short As[128 * 32];
    __shared__ __attribute__((aligned(16))) short Bs[128 * 32];

    const int tid  = threadIdx.x;
    const int lane = tid & 63;
    const int wave = tid >> 6;

    // ---- XCD-aware bijective block swizzle ----
    const unsigned gx   = gridDim.x;
    const unsigned gxy  = gx * gridDim.y;
    const unsigned total = gxy * gridDim.z;
    const unsigned orig = blockIdx.x + gx * blockIdx.y + gxy * blockIdx.z;
    unsigned wg = orig;
    if ((total & 7u) == 0u)
        wg = (orig & 7u) * (total >> 3) + (orig >> 3);
    const unsigned bz  = wg / gxy;
    const unsigned rem = wg - bz * gxy;
    const unsigned byy = rem / gx;
    const unsigned bxx = rem - byy * gx;

    const int b    = (int)bz;
    const int m0   = (int)byy * 128;
    const int n0   = (int)bxx * 128;

    const unsigned short* Ab = A  + (long)b * strideA;
    const unsigned short* Bb = Bm + (long)b * strideB;

    // staging: chunk c covers 16B; physical (row = c>>2, phys seg = c&3).
    // swizzle: logical (global) segment = (c&3) ^ ((c>>3)&3); identical for
    // c and c+256, so one seg value serves both halves.
    const int rowL = tid >> 2;            // chunks 0..255  -> rows 0..63
    const int rowH = (tid + 256) >> 2;    // chunks 256..511-> rows 64..127
    const int seg  = (((tid & 3) ^ ((tid >> 3) & 3)) * 8);

    const unsigned short* gA0 = Ab + (long)(m0 + rowL) * lda + seg;
    const unsigned short* gA1 = Ab + (long)(m0 + rowH) * lda + seg;
    const unsigned short* gB0 = Bb + (long)(n0 + rowL) * ldb + seg;
    const unsigned short* gB1 = Bb + (long)(n0 + rowH) * ldb + seg;

    // wave-uniform LDS bases (bytes = chunk*16 -> shorts = chunk*8)
    short* lA0 = As + ((tid & ~63) + 0)   * 8;
    short* lA1 = As + ((tid & ~63) + 256) * 8;
    short* lB0 = Bs + ((tid & ~63) + 0)   * 8;
    short* lB1 = Bs + ((tid & ~63) + 256) * 8;

    const int q = lane >> 4, r = lane & 15;
    const int wm = (wave & 1) * 64, wn = (wave >> 1) * 64;
    const int sphys = (q ^ ((r >> 1) & 3)) * 8;   // swizzled fragment segment

    const short* pa[4];
    const short* pb[4];
#pragma unroll
    for (int t = 0; t < 4; ++t) {
        pa[t] = As + (wm + t * 16 + r) * 32 + sphys;
        pb[t] = Bs + (wn + t * 16 + r) * 32 + sphys;
    }

    f32x4 acc[4][4] = {};

    for (int k0 = 0; k0 < K; k0 += 32) {
        __syncthreads();
        __builtin_amdgcn_global_load_lds(
            (const __attribute__((address_space(1))) void*)(gA0 + k0),
            (__attribute__((address_space(3))) void*)lA0, 16, 0, 0);
        __builtin_amdgcn_global_load_lds(
            (const __attribute__((address_space(1))) void*)(gB0 + k0),
            (__attribute__((address_space(3))) void*)lB0, 16, 0, 0);
        __builtin_amdgcn_global_load_lds(
            (const __attribute__((address_space(1))) void*)(gA1 + k0),
            (__attribute__((address_space(3))) void*)lA1, 16, 0, 0);
        __builtin_amdgcn_global_load_lds(
            (const __attribute__((address_space(1))) void*)(gB1 + k0),
            (__attribute__((address_space(3))) void*)lB1, 16, 0, 0);
        __syncthreads();

        short8 af[4], bf[4];
#pragma unroll
        for (int t = 0; t < 4; ++t) {
            af[t] = *(const short8*)pa[t];
            bf[t] = *(const short8*)pb[t];
        }
#pragma unroll
        for (int mt = 0; mt < 4; ++mt)
#pragma unroll
            for (int nt = 0; nt < 4; ++nt)
                acc[mt][nt] = __builtin_amdgcn_mfma_f32_16x16x32_bf16(
                    af[mt], bf[nt], acc[mt][nt], 0, 0, 0);
    }

    // epilogue: C/D layout col = lane&15, row = (lane>>4)*4 + reg
    if (OUT_MODE == 1) {
        unsigned short* C = (unsigned short*)Cout + (long)b * strideC;
#pragma unroll
        for (int mt = 0; mt < 4; ++mt)
#pragma unroll
            for (int nt = 0; nt < 4; ++nt)
#pragma unroll
                for (int rr = 0; rr < 4; ++rr) {
                    const int grow = m0 + wm + mt * 16 + q * 4 + rr;
                    const int gcol = n0 + wn + nt * 16 + r;
                    C[(long)grow * ldc + gcol] = f2bf(acc[mt][nt][rr]);
                }
    } else if (OUT_MODE == 0) {
        float* C = (float*)Cout + (long)b * strideC;
#pragma unroll
        for (int mt = 0; mt < 4; ++mt)
#pragma unroll
            for (int nt = 0; nt < 4; ++nt)
#pragma unroll
                for (int rr = 0; rr < 4; ++rr) {
                    const int grow = m0 + wm + mt * 16 + q * 4 + rr;
                    const int gcol = n0 + wn + nt * 16 + r;
                    C[(long)grow * ldc + gcol] = acc[mt][nt][rr];
                }
    } else {
        const int Lb = Lp[b];
        float* C = (float*)Cout + (long)b * strideC;
#pragma unroll
        for (int mt = 0; mt < 4; ++mt)
#pragma unroll
            for (int nt = 0; nt < 4; ++nt)
#pragma unroll
                for (int rr = 0; rr < 4; ++rr) {
                    const int grow = m0 + wm + mt * 16 + q * 4 + rr;
                    const int gcol = n0 + wn + nt * 16 + r;
                    const float val = (grow < Lb && gcol < Lb) ? acc[mt][nt][rr] : NEGV;
                    C[(long)grow * ldc + gcol] = val;
                }
    }
}

// ---------------------------------------------------------------------------
// In-place row softmax over last dim (N_=2048). One block per row.
// ---------------------------------------------------------------------------
__global__ __launch_bounds__(256)
void softmax_rows(float* __restrict__ Att)
{
    const size_t row = blockIdx.x;
    float* p = Att + row * (size_t)N_;
    const int t = threadIdx.x;

    float4 v0 = *(float4*)(p + t * 4);
    float4 v1 = *(float4*)(p + 1024 + t * 4);

    float mx = fmaxf(fmaxf(fmaxf(v0.x, v0.y), fmaxf(v0.z, v0.w)),
                     fmaxf(fmaxf(v1.x, v1.y), fmaxf(v1.z, v1.w)));
#pragma unroll
    for (int o = 32; o > 0; o >>= 1) mx = fmaxf(mx, __shfl_xor(mx, o, 64));

    __shared__ float red[8];
    const int wv = t >> 6;
    if ((t & 63) == 0) red[wv] = mx;
    __syncthreads();
    mx = fmaxf(fmaxf(red[0], red[1]), fmaxf(red[2], red[3]));

    float e[8];
    e[0] = expf(v0.x - mx); e[1] = expf(v0.y - mx);
    e[2] = expf(v0.z - mx); e[3] = expf(v0.w - mx);
    e[4] = expf(v1.x - mx); e[5] = expf(v1.y - mx);
    e[6] = expf(v1.z - mx); e[7] = expf(v1.w - mx);
    float s = ((e[0] + e[1]) + (e[2] + e[3])) + ((e[4] + e[5]) + (e[6] + e[7]));
#pragma unroll
    for (int o = 32; o > 0; o >>= 1) s += __shfl_xor(s, o, 64);
    if ((t & 63) == 0) red[4 + wv] = s;
    __syncthreads();
    const float inv = 1.0f / (red[4] + red[5] + red[6] + red[7]);

    *(float4*)(p + t * 4)        = make_float4(e[0] * inv, e[1] * inv, e[2] * inv, e[3] * inv);
    *(float4*)(p + 1024 + t * 4) = make_float4(e[4] * inv, e[5] * inv, e[6] * inv, e[7] * inv);
}

// ---------------------------------------------------------------------------
// att f32 [b][j][i] -> attT bf16 [b][i][j], 64x64 LDS tile transpose.
// ---------------------------------------------------------------------------
__global__ __launch_bounds__(256)
void transpose_att_bf16(const float* __restrict__ att, unsigned short* __restrict__ attT)
{
    __shared__ float tile[64][65];
    const int b  = blockIdx.z;
    const int j0 = blockIdx.y * 64;
    const int i0 = blockIdx.x * 64;
    const float* src = att + (long)b * N_ * N_;
    unsigned short* dst = attT + (long)b * N_ * N_;
    const int t = threadIdx.x;
#pragma unroll
    for (int l = 0; l < 4; ++l) {
        const int idx = t + l * 256;
        const int jj = idx >> 4;
        const int i4 = (idx & 15) * 4;
        const float4 v = *(const float4*)(src + (long)(j0 + jj) * N_ + i0 + i4);
        tile[i4 + 0][jj] = v.x;
        tile[i4 + 1][jj] = v.y;
        tile[i4 + 2][jj] = v.z;
        tile[i4 + 3][jj] = v.w;
    }
    __syncthreads();
#pragma unroll
    for (int l = 0; l < 4; ++l) {
        const int idx = t + l * 256;
        const int ii = idx >> 4;
        const int j4 = (idx & 15) * 4;
        ushort4 o;
        o.x = f2bf(tile[ii][j4 + 0]);
        o.y = f2bf(tile[ii][j4 + 1]);
        o.z = f2bf(tile[ii][j4 + 2]);
        o.w = f2bf(tile[ii][j4 + 3]);
        *(ushort4*)(dst + (long)(i0 + ii) * N_ + j0 + j4) = o;
    }
}

// ---------------------------------------------------------------------------
// V slice of QKV [16384 tokens][3072] (cols 2048..3071) -> VT bf16 [1024][16384]
// 64x64 LDS tile transpose, bf16 in / bf16 out.
// ---------------------------------------------------------------------------
__global__ __launch_bounds__(256)
void transpose_v_bf16(const unsigned short* __restrict__ qkv, unsigned short* __restrict__ vt)
{
    __shared__ unsigned short tile[64][68];
    const int j0 = blockIdx.x * 64;   // token dim (16384/64 = 256 blocks)
    const int d0 = blockIdx.y * 64;   // d dim (1024/64 = 16 blocks)
    const int t = threadIdx.x;
#pragma unroll
    for (int l = 0; l < 4; ++l) {
        const int idx = t + l * 256;      // 0..1023
        const int jj = idx >> 4;          // token row 0..63
        const int d4 = (idx & 15) * 4;    // d col 0..60
        const ushort4 v = *(const ushort4*)(qkv + (long)(j0 + jj) * 3072 + 2048 + d0 + d4);
        tile[d4 + 0][jj] = v.x;
        tile[d4 + 1][jj] = v.y;
        tile[d4 + 2][jj] = v.z;
        tile[d4 + 3][jj] = v.w;
    }
    __syncthreads();
#pragma unroll
    for (int l = 0; l < 4; ++l) {
        const int idx = t + l * 256;
        const int dd = idx >> 4;          // d row 0..63
        const int j4 = (idx & 15) * 4;    // token col
        ushort4 o;
        o.x = tile[dd][j4 + 0];
        o.y = tile[dd][j4 + 1];
        o.z = tile[dd][j4 + 2];
        o.w = tile[dd][j4 + 3];
        *(ushort4*)(vt + (long)(d0 + dd) * 16384 + j0 + j4) = o;
    }
}

// ---------------------------------------------------------------------------
extern "C" void kernel_launch(void* const* d_in, const int* in_sizes, int n_in,
                              void* d_out, int out_size, void* d_ws, size_t ws_size,
                              hipStream_t stream)
{
    const float* x  = (const float*)d_in[0];
    const unsigned char* mask = (const unsigned char*)d_in[1];
    const float* Wq = (const float*)d_in[2];
    const float* Wk = (const float*)d_in[3];
    const float* Wv = (const float*)d_in[4];
    const float* Wo = (const float*)d_in[5];

    float* y   = (float*)d_out;                          // [B,N,D] f32
    float* att = (float*)d_out + (size_t)B_ * N_ * D_;   // [B,N,N] f32

    char* ws = (char*)d_ws;
    int* L = (int*)ws;
    unsigned short* Wqkvb = (unsigned short*)(ws + 256); // [3072,1024] (Q|K|V rows)
    unsigned short* Wob   = Wqkvb + 3145728;             // [1024,1024]
    unsigned short* xb    = Wob + 1048576;               // [16384,1024]
    unsigned short* QKVb  = xb + 16777216;               // [16384,3072]
    unsigned short* VT    = QKVb + 50331648;             // [1024,16384]
    unsigned short* attT  = QKVb;                        // [B,N,N] bf16 (reuses QKV, 64/96MB)
    unsigned short* ctx   = xb;                          // [16384,1024] bf16 (reuses xb)

    const dim3 blk(256);
    const long NN = (long)N_ * N_;
    const long ND = (long)N_ * D_;
    const long NQ = (long)N_ * 3072;                     // row stride of one batch in QKV

    k_lengths<<<dim3(B_), blk, 0, stream>>>(mask, L);

    convert_bf16<<<dim3(16384), blk, 0, stream>>>(x,  xb,  4194304, 1.0f);
    convert_bf16<<<dim3(1024),  blk, 0, stream>>>(Wq, Wqkvb,           262144, 0.06f);
    convert_bf16<<<dim3(1024),  blk, 0, stream>>>(Wk, Wqkvb + 1048576, 262144, 1.0f);
    convert_bf16<<<dim3(1024),  blk, 0, stream>>>(Wv, Wqkvb + 2097152, 262144, 1.0f);
    convert_bf16<<<dim3(1024),  blk, 0, stream>>>(Wo, Wob,             262144, 1.0f);

    // Fused QKV = x @ [Wq*0.06 | Wk | Wv]^T -> [16384, 3072] bf16 (one x pass)
    gemm_nt_mfma<1><<<dim3(24, 128, 1), blk, 0, stream>>>(
        xb, D_, 0, Wqkvb, D_, 0, QKVb, 3072, 0, D_, nullptr);

    // VT[d][b*N+j] = V[b*N+j][d]  (bf16 transpose of the V slice)
    transpose_v_bf16<<<dim3(256, 16), blk, 0, stream>>>(QKVb, VT);

    // logits = Q K^T with prefix mask (f32 out into att region)
    gemm_nt_mfma<2><<<dim3(16, 16, B_), blk, 0, stream>>>(
        QKVb, 3072, NQ, QKVb + 1024, 3072, NQ, att, N_, NN, D_, L);

    softmax_rows<<<dim3(B_ * N_), blk, 0, stream>>>(att);

    // attT bf16 (reuses QKV space; Q/K/V all consumed by now)
    transpose_att_bf16<<<dim3(32, 32, B_), blk, 0, stream>>>(att, attT);

    // ctx[b][i][d] = sum_j attT[b][i][j] * VT[d][b*N + j]   (bf16 out)
    gemm_nt_mfma<1><<<dim3(8, 16, B_), blk, 0, stream>>>(
        attT, N_, NN, VT, B_ * N_, N_, ctx, D_, ND, N_, nullptr);

    // y = ctx Wo^T (f32 out)
    gemm_nt_mfma<0><<<dim3(8, 128, 1), blk, 0, stream>>>(
        ctx, D_, 0, Wob, D_, 0, y, D_, 0, D_, nullptr);
}